// Round 7
// baseline (101267.041 us; speedup 1.0000x reference)
//
#include <hip/hip_runtime.h>
#include <hip/hip_bf16.h>

typedef __bf16 bf16x8 __attribute__((ext_vector_type(8)));
typedef __bf16 bf16x4 __attribute__((ext_vector_type(4)));
typedef float  f32x4  __attribute__((ext_vector_type(4)));
typedef unsigned int u32x2 __attribute__((ext_vector_type(2)));
typedef unsigned int u32x4 __attribute__((ext_vector_type(4)));

#define NSTEP 2048
#define NB    32     // batch
#define DH    1024   // hidden = d_model = d_res
#define MTOT  (NSTEP * NB)   // 65536
#define NWORK 32     // worker WGs in rnn_scan
#define NGRID 2048   // claim-pool grid for rnn_scan

__device__ __forceinline__ f32x4 mfma16(bf16x8 a, bf16x8 b, f32x4 c) {
    return __builtin_amdgcn_mfma_f32_16x16x32_bf16(a, b, c, 0, 0, 0);
}

__device__ __forceinline__ void load_lds16(const __bf16* g, void* l) {
    __builtin_amdgcn_global_load_lds(
        (const __attribute__((address_space(1))) void*)g,
        (__attribute__((address_space(3))) void*)l, 16, 0, 0);
}

__device__ __forceinline__ float tanh_fast(float x) {
    float e = exp2f(x * 2.8853900817779268f);
    return 1.0f - 2.0f * __builtin_amdgcn_rcpf(e + 1.0f);
}

// ---------------- prep: convert weights to bf16, sum biases, zero sync -----
// Sync vars zeroed with sc0 sc1 stores so zeros reach the coherence point
// (MALL) for the device-scope atomics/polls in rnn_scan's claim phase.
__global__ __launch_bounds__(256) void prep_kernel(
    const float* __restrict__ Wih, const float* __restrict__ Whh,
    const float* __restrict__ Wout, const float* __restrict__ bih,
    const float* __restrict__ bhh,
    __bf16* __restrict__ Wih_b, __bf16* __restrict__ Whh_b,
    __bf16* __restrict__ Wout_b, float* __restrict__ bias,
    int* __restrict__ sync)
{
    const int i = blockIdx.x * 256 + threadIdx.x;   // 0..262143
    const size_t off = (size_t)i * 4;
    {
        float4 a = *(const float4*)(Wih + off);
        bf16x4 o = {(__bf16)a.x, (__bf16)a.y, (__bf16)a.z, (__bf16)a.w};
        *(bf16x4*)(Wih_b + off) = o;
    }
    {
        float4 a = *(const float4*)(Whh + off);
        bf16x4 o = {(__bf16)a.x, (__bf16)a.y, (__bf16)a.z, (__bf16)a.w};
        *(bf16x4*)(Whh_b + off) = o;
    }
    {
        float4 a = *(const float4*)(Wout + off);
        bf16x4 o = {(__bf16)a.x, (__bf16)a.y, (__bf16)a.z, (__bf16)a.w};
        *(bf16x4*)(Wout_b + off) = o;
    }
    if (i < DH) bias[i] = bih[i] + bhh[i];
    if (i < 64) {
        int z = 0;
        asm volatile("global_store_dword %0, %1, off sc0 sc1"
                     :: "v"(&sync[i]), "v"(z) : "memory");
    }
}

// ---------------- x fp32 -> bf16 -----------------------------------------
__global__ __launch_bounds__(256) void cvt_bf16_x(
    const float* __restrict__ in, __bf16* __restrict__ outb)
{
    const size_t i = ((size_t)blockIdx.x * 256 + threadIdx.x) * 8;
    float4 a = *(const float4*)(in + i);
    float4 b = *(const float4*)(in + i + 4);
    bf16x8 o = { (__bf16)a.x, (__bf16)a.y, (__bf16)a.z, (__bf16)a.w,
                 (__bf16)b.x, (__bf16)b.y, (__bf16)b.z, (__bf16)b.w };
    *(bf16x8*)(outb + i) = o;
}

// ---------------- bf16 GEMM, C = A(MxK) * B(NxK)^T (+bias), bf16 out ------
__global__ __launch_bounds__(256) void gemm_bt(
    const __bf16* __restrict__ A,
    const __bf16* __restrict__ B,
    const float*  __restrict__ bias,
    __bf16* __restrict__ C,
    int M, int N, int K)
{
    __shared__ __bf16 sA[128 * 64];
    __shared__ __bf16 sB[128 * 64];
    const int nTn = N >> 7;
    const int tm = (int)(blockIdx.x / nTn) << 7;
    const int tn = (int)(blockIdx.x % nTn) << 7;
    const int t = threadIdx.x;
    const int w = t >> 6, l = t & 63;
    const int wy = w & 1, wx = w >> 1;
    const int l16 = l & 15, lhi = l >> 4;
    const int rw = t >> 3;
    const int kc = (t & 7) << 3;

    const __bf16* ga = A + (size_t)(tm + rw) * K + kc;
    const __bf16* gb = B + (size_t)(tn + rw) * K + kc;
    char* lA = (char*)sA + (w * 8) * 128;
    char* lB = (char*)sB + (w * 8) * 128;

    f32x4 acc[4][4] = {};

    for (int k0 = 0; k0 < K; k0 += 64) {
#pragma unroll
        for (int i = 0; i < 4; ++i) {
            load_lds16(ga + (size_t)(i * 32) * K + k0, lA + i * 32 * 128);
            load_lds16(gb + (size_t)(i * 32) * K + k0, lB + i * 32 * 128);
        }
        asm volatile("s_waitcnt vmcnt(0)" ::: "memory");
        __syncthreads();
#pragma unroll
        for (int kk = 0; kk < 2; ++kk) {
            bf16x8 af[4], bfr[4];
#pragma unroll
            for (int i = 0; i < 4; ++i) {
                af[i]  = *(const bf16x8*)(sA + (wy * 64 + i * 16 + l16) * 64 + kk * 32 + lhi * 8);
                bfr[i] = *(const bf16x8*)(sB + (wx * 64 + i * 16 + l16) * 64 + kk * 32 + lhi * 8);
            }
#pragma unroll
            for (int i = 0; i < 4; ++i)
#pragma unroll
                for (int j = 0; j < 4; ++j)
                    acc[i][j] = mfma16(af[i], bfr[j], acc[i][j]);
        }
        __syncthreads();
    }
#pragma unroll
    for (int j = 0; j < 4; ++j) {
        const int col = tn + wx * 64 + j * 16 + l16;
        const float bv = bias ? bias[col] : 0.0f;
#pragma unroll
        for (int i = 0; i < 4; ++i) {
            __bf16* cp = C + (size_t)(tm + wy * 64 + i * 16 + lhi * 4) * N + col;
#pragma unroll
            for (int r = 0; r < 4; ++r)
                cp[(size_t)r * N] = (__bf16)(acc[i][j][r] + bv);
        }
    }
}

// ---------------- persistent RNN scan: XCD-claimed workers ----------------
// 2048 candidate WGs. XCC_ID==0 WGs claim the 32 worker slots immediately
// (device-scope atomics on sc0sc1-initialized memory — placement-independent
// correctness); others wait ~135us and claim only if slots remain, else exit.
// Workers publish XCC_IDs; if all 32 match, h exchange uses sc0-only ops
// (one shared XCD L2 = coherence point, ~100x lower latency than MALL);
// otherwise falls back to the proven sc0 sc1 path (R6 behavior).
// Exchange protocol: tag-in-data (2-bit epoch in each bf16's low mantissa),
// no flags, no store drains; hs memset to 0 each launch.
#define LOAD_F(dst, base, OFF) \
    asm volatile("global_load_dwordx4 %0, %1, off offset:" #OFF " sc0" \
                 : "=v"(dst) : "v"(base) : "memory");
#define LOAD_S(dst, base, OFF) \
    asm volatile("global_load_dwordx4 %0, %1, off offset:" #OFF " sc0 sc1" \
                 : "=v"(dst) : "v"(base) : "memory");
#define LOAD32(LD, ar, hb) \
    LD(ar[0],  hb, 0)    LD(ar[1],  hb, 64)   LD(ar[2],  hb, 128)  LD(ar[3],  hb, 192) \
    LD(ar[4],  hb, 256)  LD(ar[5],  hb, 320)  LD(ar[6],  hb, 384)  LD(ar[7],  hb, 448) \
    LD(ar[8],  hb, 512)  LD(ar[9],  hb, 576)  LD(ar[10], hb, 640)  LD(ar[11], hb, 704) \
    LD(ar[12], hb, 768)  LD(ar[13], hb, 832)  LD(ar[14], hb, 896)  LD(ar[15], hb, 960) \
    LD(ar[16], hb, 1024) LD(ar[17], hb, 1088) LD(ar[18], hb, 1152) LD(ar[19], hb, 1216) \
    LD(ar[20], hb, 1280) LD(ar[21], hb, 1344) LD(ar[22], hb, 1408) LD(ar[23], hb, 1472) \
    LD(ar[24], hb, 1536) LD(ar[25], hb, 1600) LD(ar[26], hb, 1664) LD(ar[27], hb, 1728) \
    LD(ar[28], hb, 1792) LD(ar[29], hb, 1856) LD(ar[30], hb, 1920) LD(ar[31], hb, 1984)

template<bool FAST>
__device__ __forceinline__ void scan_worker(
    int g, int t,
    const __bf16* __restrict__ Whh,
    const __bf16* __restrict__ pre,
    __bf16* __restrict__ hs)
{
    const int w = t >> 6;              // 0..3
    const int l = t & 63;
    const int mhalf = w & 1;
    const int nh = w >> 1;             // 0..1
    const int j0 = g * 32 + nh * 16;   // wave's 16 output cols (W rows)
    const int l16 = l & 15;
    const int lhi = l >> 4;
    const int b  = mhalf * 16 + l16;   // batch row this lane consumes/produces
    const int jc = j0 + lhi * 4;       // 4 output cols this lane stores

    // A-operand (W rows j0..j0+15): wreg[c] covers k in [c*32, c*32+32)
    bf16x8 wreg[32];
    {
        const __bf16* wb = Whh + (size_t)(j0 + l16) * DH + lhi * 8;
#pragma unroll
        for (int c = 0; c < 32; ++c)
            wreg[c] = *(const bf16x8*)(wb + c * 32);
    }
    const size_t h_off = (size_t)b * DH + lhi * 8;

    for (int s = 0; s < NSTEP; ++s) {
        bf16x4 pv = *(const bf16x4*)(pre + ((size_t)s * NB + b) * DH + jc);

        f32x4 acc0 = {0.f, 0.f, 0.f, 0.f}, acc1 = acc0, acc2 = acc0, acc3 = acc0;

        if (s > 0) {
            const __bf16* hb = hs + (size_t)(s - 1) * (NB * DH) + h_off;
            const unsigned rep = (unsigned)(((s - 1) & 1) + 1) * 0x00010001u;
            u32x4 ar[32];
            for (;;) {
                if constexpr (FAST) { LOAD32(LOAD_F, ar, hb) }
                else                { LOAD32(LOAD_S, ar, hb) }
                asm volatile("s_waitcnt vmcnt(0)" ::: "memory");
                __builtin_amdgcn_sched_barrier(0);
                unsigned bad = 0;
#pragma unroll
                for (int c = 0; c < 32; ++c) {
                    bad |= (ar[c][0] ^ rep) | (ar[c][1] ^ rep)
                         | (ar[c][2] ^ rep) | (ar[c][3] ^ rep);
                }
                if (__all((bad & 0x00030003u) == 0u)) break;
            }
            __builtin_amdgcn_sched_barrier(0);
#pragma unroll
            for (int c = 0; c < 32; c += 4) {
                acc0 = mfma16(wreg[c + 0], __builtin_bit_cast(bf16x8, ar[c + 0]), acc0);
                acc1 = mfma16(wreg[c + 1], __builtin_bit_cast(bf16x8, ar[c + 1]), acc1);
                acc2 = mfma16(wreg[c + 2], __builtin_bit_cast(bf16x8, ar[c + 2]), acc2);
                acc3 = mfma16(wreg[c + 3], __builtin_bit_cast(bf16x8, ar[c + 3]), acc3);
            }
        }
        f32x4 accs = (acc0 + acc1) + (acc2 + acc3);

        float h0 = tanh_fast(accs[0] + (float)pv[0]);
        float h1 = tanh_fast(accs[1] + (float)pv[1]);
        float h2 = tanh_fast(accs[2] + (float)pv[2]);
        float h3 = tanh_fast(accs[3] + (float)pv[3]);
        const unsigned tag = (unsigned)((s & 1) + 1);
        unsigned u0 = (unsigned)__builtin_bit_cast(unsigned short, (__bf16)h0);
        unsigned u1 = (unsigned)__builtin_bit_cast(unsigned short, (__bf16)h1);
        unsigned u2 = (unsigned)__builtin_bit_cast(unsigned short, (__bf16)h2);
        unsigned u3 = (unsigned)__builtin_bit_cast(unsigned short, (__bf16)h3);
        u0 = ((u0 + 2u) & 0xFFFCu) | tag;
        u1 = ((u1 + 2u) & 0xFFFCu) | tag;
        u2 = ((u2 + 2u) & 0xFFFCu) | tag;
        u3 = ((u3 + 2u) & 0xFFFCu) | tag;
        u32x2 uval;
        uval[0] = u0 | (u1 << 16);
        uval[1] = u2 | (u3 << 16);
        __bf16* op = hs + ((size_t)s * NB + b) * DH + jc;
        if constexpr (FAST) {
            asm volatile("global_store_dwordx2 %0, %1, off sc0"
                         :: "v"(op), "v"(uval) : "memory");
        } else {
            asm volatile("global_store_dwordx2 %0, %1, off sc0 sc1"
                         :: "v"(op), "v"(uval) : "memory");
        }
        // no drain, no flag: consumers validate the data itself
    }
}

__global__ __launch_bounds__(256, 1) void rnn_scan(
    const __bf16* __restrict__ Whh,   // [1024][1024] bf16 (row j, col k)
    const __bf16* __restrict__ pre,   // [2048][32][1024] bf16
    __bf16* __restrict__ hs,          // [2048][32][1024] bf16
    int* __restrict__ sync)           // [0]=claim counter, [8..39]=xcc publish
{
    __shared__ int sslot, sxcc, sfast;
    const int t = threadIdx.x;

    if (t == 0) {
        unsigned xcc;
        asm volatile("s_getreg_b32 %0, hwreg(HW_REG_XCC_ID)" : "=s"(xcc));
        int slot = -1;
        if (xcc == 0) {
            slot = __hip_atomic_fetch_add(&sync[0], 1, __ATOMIC_RELAXED,
                                          __HIP_MEMORY_SCOPE_AGENT);
        } else {
            // give XCD0 WGs priority; claim only if slots remain (no deadlock:
            // all 2048 candidates eventually try, so 32 always get claimed)
            for (int it = 0; it < 40; ++it) {
                __builtin_amdgcn_s_sleep(127);
                if (__hip_atomic_load(&sync[0], __ATOMIC_RELAXED,
                                      __HIP_MEMORY_SCOPE_AGENT) >= NWORK) break;
            }
            if (__hip_atomic_load(&sync[0], __ATOMIC_RELAXED,
                                  __HIP_MEMORY_SCOPE_AGENT) < NWORK)
                slot = __hip_atomic_fetch_add(&sync[0], 1, __ATOMIC_RELAXED,
                                              __HIP_MEMORY_SCOPE_AGENT);
        }
        sslot = slot;
        sxcc = (int)xcc;
    }
    __syncthreads();
    const int g = sslot;
    if ((unsigned)g >= (unsigned)NWORK) return;

    // publish my XCD, then check whether all 32 workers share one XCD
    if (t < 64) {
        if (t == 0) {
            int pub = sxcc + 1;
            asm volatile("global_store_dword %0, %1, off sc0 sc1\n\t"
                         "s_waitcnt vmcnt(0)"
                         :: "v"(&sync[8 + g]), "v"(pub) : "memory");
        }
        const int* pp = sync + 8 + (t & 31);
        int v;
        for (;;) {
            asm volatile("global_load_dword %0, %1, off sc0 sc1\n\t"
                         "s_waitcnt vmcnt(0)"
                         : "=v"(v) : "v"(pp) : "memory");
            __builtin_amdgcn_sched_barrier(0);
            if (__all(v != 0)) break;
        }
        int v0 = __shfl(v, 0);
        if (t == 0) sfast = __all(v == v0) ? 1 : 0;
    }
    __syncthreads();

    if (sfast) scan_worker<true >(g, t, Whh, pre, hs);
    else       scan_worker<false>(g, t, Whh, pre, hs);
}

// ---------------- fused residual + LayerNorm ------------------------------
__global__ __launch_bounds__(256) void fused_ln(
    const float* __restrict__ x,
    const __bf16* __restrict__ attn,
    const float* __restrict__ gam,
    const float* __restrict__ bet,
    float* __restrict__ out)
{
    const int row = blockIdx.x;
    const int t = threadIdx.x;
    const size_t base = (size_t)row * DH + t * 4;
    float4 xv = *(const float4*)(x + base);
    bf16x4 av = *(const bf16x4*)(attn + base);
    float v0 = xv.x + (float)av[0];
    float v1 = xv.y + (float)av[1];
    float v2 = xv.z + (float)av[2];
    float v3 = xv.w + (float)av[3];
    float s1 = v0 + v1 + v2 + v3;
    float s2 = v0 * v0 + v1 * v1 + v2 * v2 + v3 * v3;
#pragma unroll
    for (int off = 32; off > 0; off >>= 1) {
        s1 += __shfl_xor(s1, off);
        s2 += __shfl_xor(s2, off);
    }
    __shared__ float red[8];
    const int w = t >> 6, l = t & 63;
    if (l == 0) { red[w] = s1; red[4 + w] = s2; }
    __syncthreads();
    float S1 = red[0] + red[1] + red[2] + red[3];
    float S2 = red[4] + red[5] + red[6] + red[7];
    const float mu = S1 * (1.0f / 1024.0f);
    const float var = S2 * (1.0f / 1024.0f) - mu * mu;
    const float rs = rsqrtf(var + 1e-5f);
    const int c = t * 4;
    float4 gv = *(const float4*)(gam + c);
    float4 bv = *(const float4*)(bet + c);
    float4 o;
    o.x = (v0 - mu) * rs * gv.x + bv.x;
    o.y = (v1 - mu) * rs * gv.y + bv.y;
    o.z = (v2 - mu) * rs * gv.z + bv.z;
    o.w = (v3 - mu) * rs * gv.w + bv.w;
    *(float4*)(out + base) = o;
}

// ---------------- launcher -------------------------------------------------
extern "C" void kernel_launch(void* const* d_in, const int* in_sizes, int n_in,
                              void* d_out, int out_size, void* d_ws, size_t ws_size,
                              hipStream_t stream)
{
    const float* x    = (const float*)d_in[0];
    const float* Wih  = (const float*)d_in[1];
    const float* Whh  = (const float*)d_in[2];
    const float* bih  = (const float*)d_in[3];
    const float* bhh  = (const float*)d_in[4];
    const float* Wout = (const float*)d_in[5];
    const float* lng  = (const float*)d_in[6];
    const float* lnb  = (const float*)d_in[7];
    float* out = (float*)d_out;

    char* ws = (char*)d_ws;
    const size_t BIG = (size_t)MTOT * DH * sizeof(__bf16);  // 134217728
    __bf16* buf0   = (__bf16*)ws;                  // x_bf16, later reused for attn
    __bf16* pre    = (__bf16*)(ws + BIG);
    __bf16* hsbuf  = (__bf16*)(ws + 2 * BIG);
    __bf16* Wih_b  = (__bf16*)(ws + 3 * BIG);
    __bf16* Whh_b  = Wih_b + (size_t)DH * DH;
    __bf16* Wout_b = Whh_b + (size_t)DH * DH;
    float*  bias   = (float*)(Wout_b + (size_t)DH * DH);
    int*    sync   = (int*)(bias + DH);

    prep_kernel<<<1024, 256, 0, stream>>>(Wih, Whh, Wout, bih, bhh,
                                          Wih_b, Whh_b, Wout_b, bias, sync);
    cvt_bf16_x<<<32768, 256, 0, stream>>>(x, buf0);
    // clear hs: tag bits 00 never match a valid epoch (kills poison + stale replays)
    hipMemsetAsync(hsbuf, 0, BIG, stream);
    gemm_bt<<<4096, 256, 0, stream>>>(buf0, Wih_b, bias, pre, MTOT, DH, DH);
    rnn_scan<<<NGRID, 256, 0, stream>>>(Whh_b, pre, hsbuf, sync);
    gemm_bt<<<4096, 256, 0, stream>>>(hsbuf, Wout_b, nullptr, buf0, MTOT, DH, DH);
    fused_ln<<<65536, 256, 0, stream>>>(x, buf0, lng, lnb, out);
}

// Round 8
// 19398.425 us; speedup vs baseline: 5.2204x; 5.2204x over previous
//
#include <hip/hip_runtime.h>
#include <hip/hip_bf16.h>

typedef __bf16 bf16x8 __attribute__((ext_vector_type(8)));
typedef __bf16 bf16x4 __attribute__((ext_vector_type(4)));
typedef float  f32x4  __attribute__((ext_vector_type(4)));
typedef unsigned int u32x2 __attribute__((ext_vector_type(2)));

#define NSTEP 2048
#define NB    32     // batch
#define DH    1024   // hidden = d_model = d_res
#define MTOT  (NSTEP * NB)   // 65536

__device__ __forceinline__ f32x4 mfma16(bf16x8 a, bf16x8 b, f32x4 c) {
    return __builtin_amdgcn_mfma_f32_16x16x32_bf16(a, b, c, 0, 0, 0);
}

__device__ __forceinline__ void load_lds16(const __bf16* g, void* l) {
    __builtin_amdgcn_global_load_lds(
        (const __attribute__((address_space(1))) void*)g,
        (__attribute__((address_space(3))) void*)l, 16, 0, 0);
}

__device__ __forceinline__ float tanh_fast(float x) {
    float e = exp2f(x * 2.8853900817779268f);
    return 1.0f - 2.0f * __builtin_amdgcn_rcpf(e + 1.0f);
}

// ---------------- prep: convert weights to bf16, sum biases ----------------
__global__ __launch_bounds__(256) void prep_kernel(
    const float* __restrict__ Wih, const float* __restrict__ Whh,
    const float* __restrict__ Wout, const float* __restrict__ bih,
    const float* __restrict__ bhh,
    __bf16* __restrict__ Wih_b, __bf16* __restrict__ Whh_b,
    __bf16* __restrict__ Wout_b, float* __restrict__ bias)
{
    const int i = blockIdx.x * 256 + threadIdx.x;   // 0..262143
    const size_t off = (size_t)i * 4;
    {
        float4 a = *(const float4*)(Wih + off);
        bf16x4 o = {(__bf16)a.x, (__bf16)a.y, (__bf16)a.z, (__bf16)a.w};
        *(bf16x4*)(Wih_b + off) = o;
    }
    {
        float4 a = *(const float4*)(Whh + off);
        bf16x4 o = {(__bf16)a.x, (__bf16)a.y, (__bf16)a.z, (__bf16)a.w};
        *(bf16x4*)(Whh_b + off) = o;
    }
    {
        float4 a = *(const float4*)(Wout + off);
        bf16x4 o = {(__bf16)a.x, (__bf16)a.y, (__bf16)a.z, (__bf16)a.w};
        *(bf16x4*)(Wout_b + off) = o;
    }
    if (i < DH) bias[i] = bih[i] + bhh[i];
}

// ---------------- x fp32 -> bf16 -----------------------------------------
__global__ __launch_bounds__(256) void cvt_bf16_x(
    const float* __restrict__ in, __bf16* __restrict__ outb)
{
    const size_t i = ((size_t)blockIdx.x * 256 + threadIdx.x) * 8;
    float4 a = *(const float4*)(in + i);
    float4 b = *(const float4*)(in + i + 4);
    bf16x8 o = { (__bf16)a.x, (__bf16)a.y, (__bf16)a.z, (__bf16)a.w,
                 (__bf16)b.x, (__bf16)b.y, (__bf16)b.z, (__bf16)b.w };
    *(bf16x8*)(outb + i) = o;
}

// ---------------- bf16 GEMM, C = A(MxK) * B(NxK)^T (+bias), bf16 out ------
__global__ __launch_bounds__(256) void gemm_bt(
    const __bf16* __restrict__ A,
    const __bf16* __restrict__ B,
    const float*  __restrict__ bias,
    __bf16* __restrict__ C,
    int M, int N, int K)
{
    __shared__ __bf16 sA[128 * 64];
    __shared__ __bf16 sB[128 * 64];
    const int nTn = N >> 7;
    const int tm = (int)(blockIdx.x / nTn) << 7;
    const int tn = (int)(blockIdx.x % nTn) << 7;
    const int t = threadIdx.x;
    const int w = t >> 6, l = t & 63;
    const int wy = w & 1, wx = w >> 1;
    const int l16 = l & 15, lhi = l >> 4;
    const int rw = t >> 3;
    const int kc = (t & 7) << 3;

    const __bf16* ga = A + (size_t)(tm + rw) * K + kc;
    const __bf16* gb = B + (size_t)(tn + rw) * K + kc;
    char* lA = (char*)sA + (w * 8) * 128;
    char* lB = (char*)sB + (w * 8) * 128;

    f32x4 acc[4][4] = {};

    for (int k0 = 0; k0 < K; k0 += 64) {
#pragma unroll
        for (int i = 0; i < 4; ++i) {
            load_lds16(ga + (size_t)(i * 32) * K + k0, lA + i * 32 * 128);
            load_lds16(gb + (size_t)(i * 32) * K + k0, lB + i * 32 * 128);
        }
        asm volatile("s_waitcnt vmcnt(0)" ::: "memory");
        __syncthreads();
#pragma unroll
        for (int kk = 0; kk < 2; ++kk) {
            bf16x8 af[4], bfr[4];
#pragma unroll
            for (int i = 0; i < 4; ++i) {
                af[i]  = *(const bf16x8*)(sA + (wy * 64 + i * 16 + l16) * 64 + kk * 32 + lhi * 8);
                bfr[i] = *(const bf16x8*)(sB + (wx * 64 + i * 16 + l16) * 64 + kk * 32 + lhi * 8);
            }
#pragma unroll
            for (int i = 0; i < 4; ++i)
#pragma unroll
                for (int j = 0; j < 4; ++j)
                    acc[i][j] = mfma16(af[i], bfr[j], acc[i][j]);
        }
        __syncthreads();
    }
#pragma unroll
    for (int j = 0; j < 4; ++j) {
        const int col = tn + wx * 64 + j * 16 + l16;
        const float bv = bias ? bias[col] : 0.0f;
#pragma unroll
        for (int i = 0; i < 4; ++i) {
            __bf16* cp = C + (size_t)(tm + wy * 64 + i * 16 + lhi * 4) * N + col;
#pragma unroll
            for (int r = 0; r < 4; ++r)
                cp[(size_t)r * N] = (__bf16)(acc[i][j][r] + bv);
        }
    }
}

// ---------------- RNN step: ONE time-step per kernel launch ----------------
// Kernel boundaries provide ordering + visibility (stream-ordered plain
// loads/stores; no sc bits, no flags, no placement assumptions). 32 WGs x 4
// waves; WG g owns output cols [g*32,g*32+32). Swapped MFMA (verified R4+):
// D[j][b] = sum_k W[j][k] h[b][k]; lane stores 4 j-consecutive bf16 = one
// aligned dwordx2. W slice (32KB/wave) re-read each launch -- L2-hot.
__global__ __launch_bounds__(256) void rnn_step(
    const __bf16* __restrict__ Whh,   // [1024][1024] bf16 (row j, col k)
    const __bf16* __restrict__ pre,   // [2048][32][1024] bf16
    __bf16* __restrict__ hs,          // [2048][32][1024] bf16
    int s)
{
    const int g = blockIdx.x;          // 0..31
    const int t = threadIdx.x;
    const int w = t >> 6;              // 0..3
    const int l = t & 63;
    const int mhalf = w & 1;
    const int nh = w >> 1;             // 0..1
    const int j0 = g * 32 + nh * 16;   // wave's 16 output cols (W rows)
    const int l16 = l & 15;
    const int lhi = l >> 4;
    const int b  = mhalf * 16 + l16;   // batch row this lane consumes/produces
    const int jc = j0 + lhi * 4;       // 4 output cols this lane stores

    bf16x4 pv = *(const bf16x4*)(pre + ((size_t)s * NB + b) * DH + jc);

    f32x4 acc0 = {0.f, 0.f, 0.f, 0.f}, acc1 = acc0, acc2 = acc0, acc3 = acc0;

    if (s > 0) {
        const __bf16* wb = Whh + (size_t)(j0 + l16) * DH + lhi * 8;
        const __bf16* hb = hs + (size_t)(s - 1) * (NB * DH) + (size_t)b * DH + lhi * 8;
#pragma unroll
        for (int c = 0; c < 32; c += 4) {
            bf16x8 w0 = *(const bf16x8*)(wb + (c + 0) * 32);
            bf16x8 w1 = *(const bf16x8*)(wb + (c + 1) * 32);
            bf16x8 w2 = *(const bf16x8*)(wb + (c + 2) * 32);
            bf16x8 w3 = *(const bf16x8*)(wb + (c + 3) * 32);
            bf16x8 h0 = *(const bf16x8*)(hb + (c + 0) * 32);
            bf16x8 h1 = *(const bf16x8*)(hb + (c + 1) * 32);
            bf16x8 h2 = *(const bf16x8*)(hb + (c + 2) * 32);
            bf16x8 h3 = *(const bf16x8*)(hb + (c + 3) * 32);
            acc0 = mfma16(w0, h0, acc0);
            acc1 = mfma16(w1, h1, acc1);
            acc2 = mfma16(w2, h2, acc2);
            acc3 = mfma16(w3, h3, acc3);
        }
    }
    f32x4 accs = (acc0 + acc1) + (acc2 + acc3);

    float h0 = tanh_fast(accs[0] + (float)pv[0]);
    float h1 = tanh_fast(accs[1] + (float)pv[1]);
    float h2 = tanh_fast(accs[2] + (float)pv[2]);
    float h3 = tanh_fast(accs[3] + (float)pv[3]);
    u32x2 uval;
    uval[0] = (unsigned)__builtin_bit_cast(unsigned short, (__bf16)h0)
            | ((unsigned)__builtin_bit_cast(unsigned short, (__bf16)h1) << 16);
    uval[1] = (unsigned)__builtin_bit_cast(unsigned short, (__bf16)h2)
            | ((unsigned)__builtin_bit_cast(unsigned short, (__bf16)h3) << 16);
    *(u32x2*)(hs + ((size_t)s * NB + b) * DH + jc) = uval;
}

// ---------------- fused residual + LayerNorm ------------------------------
__global__ __launch_bounds__(256) void fused_ln(
    const float* __restrict__ x,
    const __bf16* __restrict__ attn,
    const float* __restrict__ gam,
    const float* __restrict__ bet,
    float* __restrict__ out)
{
    const int row = blockIdx.x;
    const int t = threadIdx.x;
    const size_t base = (size_t)row * DH + t * 4;
    float4 xv = *(const float4*)(x + base);
    bf16x4 av = *(const bf16x4*)(attn + base);
    float v0 = xv.x + (float)av[0];
    float v1 = xv.y + (float)av[1];
    float v2 = xv.z + (float)av[2];
    float v3 = xv.w + (float)av[3];
    float s1 = v0 + v1 + v2 + v3;
    float s2 = v0 * v0 + v1 * v1 + v2 * v2 + v3 * v3;
#pragma unroll
    for (int off = 32; off > 0; off >>= 1) {
        s1 += __shfl_xor(s1, off);
        s2 += __shfl_xor(s2, off);
    }
    __shared__ float red[8];
    const int w = t >> 6, l = t & 63;
    if (l == 0) { red[w] = s1; red[4 + w] = s2; }
    __syncthreads();
    float S1 = red[0] + red[1] + red[2] + red[3];
    float S2 = red[4] + red[5] + red[6] + red[7];
    const float mu = S1 * (1.0f / 1024.0f);
    const float var = S2 * (1.0f / 1024.0f) - mu * mu;
    const float rs = rsqrtf(var + 1e-5f);
    const int c = t * 4;
    float4 gv = *(const float4*)(gam + c);
    float4 bv = *(const float4*)(bet + c);
    float4 o;
    o.x = (v0 - mu) * rs * gv.x + bv.x;
    o.y = (v1 - mu) * rs * gv.y + bv.y;
    o.z = (v2 - mu) * rs * gv.z + bv.z;
    o.w = (v3 - mu) * rs * gv.w + bv.w;
    *(float4*)(out + base) = o;
}

// ---------------- launcher -------------------------------------------------
extern "C" void kernel_launch(void* const* d_in, const int* in_sizes, int n_in,
                              void* d_out, int out_size, void* d_ws, size_t ws_size,
                              hipStream_t stream)
{
    const float* x    = (const float*)d_in[0];
    const float* Wih  = (const float*)d_in[1];
    const float* Whh  = (const float*)d_in[2];
    const float* bih  = (const float*)d_in[3];
    const float* bhh  = (const float*)d_in[4];
    const float* Wout = (const float*)d_in[5];
    const float* lng  = (const float*)d_in[6];
    const float* lnb  = (const float*)d_in[7];
    float* out = (float*)d_out;

    char* ws = (char*)d_ws;
    const size_t BIG = (size_t)MTOT * DH * sizeof(__bf16);  // 134217728
    __bf16* buf0   = (__bf16*)ws;                  // x_bf16, later reused for attn
    __bf16* pre    = (__bf16*)(ws + BIG);
    __bf16* hsbuf  = (__bf16*)(ws + 2 * BIG);
    __bf16* Wih_b  = (__bf16*)(ws + 3 * BIG);
    __bf16* Whh_b  = Wih_b + (size_t)DH * DH;
    __bf16* Wout_b = Whh_b + (size_t)DH * DH;
    float*  bias   = (float*)(Wout_b + (size_t)DH * DH);

    prep_kernel<<<1024, 256, 0, stream>>>(Wih, Whh, Wout, bih, bhh,
                                          Wih_b, Whh_b, Wout_b, bias);
    cvt_bf16_x<<<32768, 256, 0, stream>>>(x, buf0);
    gemm_bt<<<4096, 256, 0, stream>>>(buf0, Wih_b, bias, pre, MTOT, DH, DH);
    for (int s = 0; s < NSTEP; ++s)
        rnn_step<<<32, 256, 0, stream>>>(Whh_b, pre, hsbuf, s);
    gemm_bt<<<4096, 256, 0, stream>>>(hsbuf, Wout_b, nullptr, buf0, MTOT, DH, DH);
    fused_ln<<<65536, 256, 0, stream>>>(x, buf0, lng, lnb, out);
}

// Round 9
// 8712.974 us; speedup vs baseline: 11.6226x; 2.2264x over previous
//
#include <hip/hip_runtime.h>
#include <hip/hip_bf16.h>

typedef __bf16 bf16x8 __attribute__((ext_vector_type(8)));
typedef __bf16 bf16x4 __attribute__((ext_vector_type(4)));
typedef float  f32x4  __attribute__((ext_vector_type(4)));
typedef unsigned int u32x2 __attribute__((ext_vector_type(2)));
typedef unsigned int u32x4 __attribute__((ext_vector_type(4)));

#define NSTEP 2048
#define NB    32     // batch
#define DH    1024   // hidden = d_model = d_res
#define MTOT  (NSTEP * NB)   // 65536
#define NWORK 16     // worker WGs in rnn_scan
#define NFILL 208    // clock-pinning filler WGs (16+208=224 < 256 CUs -> all resident)
#define FILLER_CAP 60000

__device__ __forceinline__ f32x4 mfma16(bf16x8 a, bf16x8 b, f32x4 c) {
    return __builtin_amdgcn_mfma_f32_16x16x32_bf16(a, b, c, 0, 0, 0);
}

__device__ __forceinline__ void load_lds16(const __bf16* g, void* l) {
    __builtin_amdgcn_global_load_lds(
        (const __attribute__((address_space(1))) void*)g,
        (__attribute__((address_space(3))) void*)l, 16, 0, 0);
}

__device__ __forceinline__ float tanh_fast(float x) {
    float e = exp2f(x * 2.8853900817779268f);
    return 1.0f - 2.0f * __builtin_amdgcn_rcpf(e + 1.0f);
}

// ---------------- prep: convert weights to bf16, sum biases, zero flags ----
__global__ __launch_bounds__(256) void prep_kernel(
    const float* __restrict__ Wih, const float* __restrict__ Whh,
    const float* __restrict__ Wout, const float* __restrict__ bih,
    const float* __restrict__ bhh,
    __bf16* __restrict__ Wih_b, __bf16* __restrict__ Whh_b,
    __bf16* __restrict__ Wout_b, float* __restrict__ bias,
    int* __restrict__ flags)
{
    const int i = blockIdx.x * 256 + threadIdx.x;   // 0..262143
    const size_t off = (size_t)i * 4;
    {
        float4 a = *(const float4*)(Wih + off);
        bf16x4 o = {(__bf16)a.x, (__bf16)a.y, (__bf16)a.z, (__bf16)a.w};
        *(bf16x4*)(Wih_b + off) = o;
    }
    {
        float4 a = *(const float4*)(Whh + off);
        bf16x4 o = {(__bf16)a.x, (__bf16)a.y, (__bf16)a.z, (__bf16)a.w};
        *(bf16x4*)(Whh_b + off) = o;
    }
    {
        float4 a = *(const float4*)(Wout + off);
        bf16x4 o = {(__bf16)a.x, (__bf16)a.y, (__bf16)a.z, (__bf16)a.w};
        *(bf16x4*)(Wout_b + off) = o;
    }
    if (i < DH) bias[i] = bih[i] + bhh[i];
    if (i < 64) {
        int z = 0;
        asm volatile("global_store_dword %0, %1, off sc0 sc1"
                     :: "v"(&flags[i]), "v"(z) : "memory");
    }
}

// ---------------- x fp32 -> bf16 -----------------------------------------
__global__ __launch_bounds__(256) void cvt_bf16_x(
    const float* __restrict__ in, __bf16* __restrict__ outb)
{
    const size_t i = ((size_t)blockIdx.x * 256 + threadIdx.x) * 8;
    float4 a = *(const float4*)(in + i);
    float4 b = *(const float4*)(in + i + 4);
    bf16x8 o = { (__bf16)a.x, (__bf16)a.y, (__bf16)a.z, (__bf16)a.w,
                 (__bf16)b.x, (__bf16)b.y, (__bf16)b.z, (__bf16)b.w };
    *(bf16x8*)(outb + i) = o;
}

// ---------------- bf16 GEMM, C = A(MxK) * B(NxK)^T (+bias), bf16 out ------
__global__ __launch_bounds__(256) void gemm_bt(
    const __bf16* __restrict__ A,
    const __bf16* __restrict__ B,
    const float*  __restrict__ bias,
    __bf16* __restrict__ C,
    int M, int N, int K)
{
    __shared__ __bf16 sA[128 * 64];
    __shared__ __bf16 sB[128 * 64];
    const int nTn = N >> 7;
    const int tm = (int)(blockIdx.x / nTn) << 7;
    const int tn = (int)(blockIdx.x % nTn) << 7;
    const int t = threadIdx.x;
    const int w = t >> 6, l = t & 63;
    const int wy = w & 1, wx = w >> 1;
    const int l16 = l & 15, lhi = l >> 4;
    const int rw = t >> 3;
    const int kc = (t & 7) << 3;

    const __bf16* ga = A + (size_t)(tm + rw) * K + kc;
    const __bf16* gb = B + (size_t)(tn + rw) * K + kc;
    char* lA = (char*)sA + (w * 8) * 128;
    char* lB = (char*)sB + (w * 8) * 128;

    f32x4 acc[4][4] = {};

    for (int k0 = 0; k0 < K; k0 += 64) {
#pragma unroll
        for (int i = 0; i < 4; ++i) {
            load_lds16(ga + (size_t)(i * 32) * K + k0, lA + i * 32 * 128);
            load_lds16(gb + (size_t)(i * 32) * K + k0, lB + i * 32 * 128);
        }
        asm volatile("s_waitcnt vmcnt(0)" ::: "memory");
        __syncthreads();
#pragma unroll
        for (int kk = 0; kk < 2; ++kk) {
            bf16x8 af[4], bfr[4];
#pragma unroll
            for (int i = 0; i < 4; ++i) {
                af[i]  = *(const bf16x8*)(sA + (wy * 64 + i * 16 + l16) * 64 + kk * 32 + lhi * 8);
                bfr[i] = *(const bf16x8*)(sB + (wx * 64 + i * 16 + l16) * 64 + kk * 32 + lhi * 8);
            }
#pragma unroll
            for (int i = 0; i < 4; ++i)
#pragma unroll
                for (int j = 0; j < 4; ++j)
                    acc[i][j] = mfma16(af[i], bfr[j], acc[i][j]);
        }
        __syncthreads();
    }
#pragma unroll
    for (int j = 0; j < 4; ++j) {
        const int col = tn + wx * 64 + j * 16 + l16;
        const float bv = bias ? bias[col] : 0.0f;
#pragma unroll
        for (int i = 0; i < 4; ++i) {
            __bf16* cp = C + (size_t)(tm + wy * 64 + i * 16 + lhi * 4) * N + col;
#pragma unroll
            for (int r = 0; r < 4; ++r)
                cp[(size_t)r * N] = (__bf16)(acc[i][j][r] + bv);
        }
    }
}

// ---------------- persistent RNN scan: LDS-staged broadcast ---------------
// 16 worker WGs x 8 waves (512 thr). WG g owns j-cols [g*64,(g+1)*64).
// Wave w: mhalf=w&1 (batch half), jg=w>>1 (16-col group). Swapped MFMA
// (verified): D[j][b]; lane stores 4 j-consecutive tagged bf16 = one aligned
// dwordx2 sc0 sc1.
// Exchange: tag-in-data (2-bit epoch in each bf16). Per step the WG stages
// the 64KB h-slab ONCE into LDS: each thread retry-loads its 8x16B slice
// uncached until tags pass (load IS the poll), ds_writes it (XOR-swizzled),
// one __syncthreads, then all 8 waves consume from LDS. Uncached read
// volume: 1MB/step (vs 4MB per-wave scheme). Double-buffered LDS: a wave
// re-writes a buffer only after the joint barrier that postdates all reads
// of it (program-order chain), so one barrier per step suffices.
// Fillers pin SCLK on remaining CUs (R6-proven), exit via done flag or cap.
#define LDU(d, p) asm volatile("global_load_dwordx4 %0, %1, off sc0 sc1" \
                               : "=v"(d) : "v"(p) : "memory");

__global__ __launch_bounds__(512, 2) void rnn_scan(
    const __bf16* __restrict__ Whh,   // [1024][1024] bf16 (row j, col k)
    const __bf16* __restrict__ pre,   // [2048][32][1024] bf16
    __bf16* __restrict__ hs,          // [2048][32][1024] bf16
    int* __restrict__ flags)          // [0] = done flag
{
    const int gb = blockIdx.x;
    if (gb >= NWORK) {
        // ---- clock-pinning filler ----
        float a = (float)(threadIdx.x + gb) * 1.0e-6f + 1.0f;
        const float m = 1.000001f, d = 0.999999f;
        const int* dp = flags;
        for (int it = 0; it < FILLER_CAP; ++it) {
#pragma unroll
            for (int u = 0; u < 128; ++u) {
                a = __builtin_fmaf(a, m, 1.0e-12f);
                a = __builtin_fmaf(a, d, -1.0e-12f);
            }
            if ((it & 15) == 0) {
                int dn;
                asm volatile("global_load_dword %0, %1, off sc0 sc1\n\t"
                             "s_waitcnt vmcnt(0)"
                             : "=v"(dn) : "v"(dp) : "memory");
                if (dn != 0) break;
            }
        }
        asm volatile("" :: "v"(a));
        return;
    }

    __shared__ char slab[2][65536];    // double-buffered h slab [32 b][1024 j]
    const int t = threadIdx.x;         // 0..511
    const int w = t >> 6;              // 0..7
    const int l = t & 63;
    const int mhalf = w & 1;
    const int jg = w >> 1;             // 0..3
    const int j0 = gb * 64 + jg * 16;  // wave's 16 output cols (W rows)
    const int l16 = l & 15;
    const int lhi = l >> 4;
    const int b  = mhalf * 16 + l16;   // batch row this lane produces/consumes
    const int jc = j0 + lhi * 4;       // 4 output cols this lane stores

    // A-operand (W rows j0..j0+15): wreg[c] covers k in [c*32, c*32+32)
    bf16x8 wreg[32];
    {
        const __bf16* wb = Whh + (size_t)(j0 + l16) * DH + lhi * 8;
#pragma unroll
        for (int c = 0; c < 32; ++c)
            wreg[c] = *(const bf16x8*)(wb + c * 32);
    }

    // LDS read geometry for this lane's B-fragments: row=b, swizzle by b&7
    const unsigned rbase = (unsigned)b * 2048 + (unsigned)lhi * 16;
    const unsigned rx = (unsigned)((b & 7) << 4);

    for (int s = 0; s < NSTEP; ++s) {
        bf16x4 pv = *(const bf16x4*)(pre + ((size_t)s * NB + b) * DH + jc);

        f32x4 acc0 = {0.f, 0.f, 0.f, 0.f}, acc1 = acc0, acc2 = acc0, acc3 = acc0;
        int bi = 0;

        if (s > 0) {
            const int sl = s - 1;
            bi = sl & 1;
            const unsigned rep = (unsigned)((sl & 1) + 1) * 0x00010001u;
            const char* sp = (const char*)hs + ((size_t)sl << 16) + (size_t)t * 16;
            const char* p0 = sp;
            const char* p1 = sp + 8192;
            const char* p2 = sp + 16384;
            const char* p3 = sp + 24576;
            const char* p4 = sp + 32768;
            const char* p5 = sp + 40960;
            const char* p6 = sp + 49152;
            const char* p7 = sp + 57344;
            u32x4 st[8];
            for (;;) {
                LDU(st[0], p0) LDU(st[1], p1) LDU(st[2], p2) LDU(st[3], p3)
                LDU(st[4], p4) LDU(st[5], p5) LDU(st[6], p6) LDU(st[7], p7)
                asm volatile("s_waitcnt vmcnt(0)" ::: "memory");
                __builtin_amdgcn_sched_barrier(0);
                unsigned bad = 0;
#pragma unroll
                for (int i = 0; i < 8; ++i)
                    bad |= (st[i][0] ^ rep) | (st[i][1] ^ rep)
                         | (st[i][2] ^ rep) | (st[i][3] ^ rep);
                if (__all((bad & 0x00030003u) == 0u)) break;
            }
            __builtin_amdgcn_sched_barrier(0);
            // ds_write slice (XOR-swizzled: row stride 2048B would 16-way conflict)
#pragma unroll
            for (int i = 0; i < 8; ++i) {
                unsigned byte = (unsigned)t * 16 + (unsigned)i * 8192;
                unsigned row = byte >> 11;
                unsigned swz = byte ^ ((row & 7) << 4);
                *(u32x4*)(&slab[bi][swz]) = st[i];
            }
            __syncthreads();
            // consume: this wave's batch-half rows, full k, from LDS
#pragma unroll
            for (int c = 0; c < 32; c += 4) {
                bf16x8 h0 = *(const bf16x8*)(&slab[bi][(rbase + (unsigned)(c + 0) * 64) ^ rx]);
                bf16x8 h1 = *(const bf16x8*)(&slab[bi][(rbase + (unsigned)(c + 1) * 64) ^ rx]);
                bf16x8 h2 = *(const bf16x8*)(&slab[bi][(rbase + (unsigned)(c + 2) * 64) ^ rx]);
                bf16x8 h3 = *(const bf16x8*)(&slab[bi][(rbase + (unsigned)(c + 3) * 64) ^ rx]);
                acc0 = mfma16(wreg[c + 0], h0, acc0);
                acc1 = mfma16(wreg[c + 1], h1, acc1);
                acc2 = mfma16(wreg[c + 2], h2, acc2);
                acc3 = mfma16(wreg[c + 3], h3, acc3);
            }
        }
        f32x4 accs = (acc0 + acc1) + (acc2 + acc3);

        float h0 = tanh_fast(accs[0] + (float)pv[0]);
        float h1 = tanh_fast(accs[1] + (float)pv[1]);
        float h2 = tanh_fast(accs[2] + (float)pv[2]);
        float h3 = tanh_fast(accs[3] + (float)pv[3]);
        // tag low 2 bits of each bf16 with epoch (round to nearest 4 ulp)
        const unsigned tag = (unsigned)((s & 1) + 1);
        unsigned u0 = (unsigned)__builtin_bit_cast(unsigned short, (__bf16)h0);
        unsigned u1 = (unsigned)__builtin_bit_cast(unsigned short, (__bf16)h1);
        unsigned u2 = (unsigned)__builtin_bit_cast(unsigned short, (__bf16)h2);
        unsigned u3 = (unsigned)__builtin_bit_cast(unsigned short, (__bf16)h3);
        u0 = ((u0 + 2u) & 0xFFFCu) | tag;
        u1 = ((u1 + 2u) & 0xFFFCu) | tag;
        u2 = ((u2 + 2u) & 0xFFFCu) | tag;
        u3 = ((u3 + 2u) & 0xFFFCu) | tag;
        u32x2 uval;
        uval[0] = u0 | (u1 << 16);
        uval[1] = u2 | (u3 << 16);
        __bf16* op = hs + ((size_t)s * NB + b) * DH + jc;
        asm volatile("global_store_dwordx2 %0, %1, off sc0 sc1"
                     :: "v"(op), "v"(uval) : "memory");
        // no drain, no flags: consumers validate the data itself
    }
    if (gb == 0 && t == 0) {
        int one = 1;
        asm volatile("global_store_dword %0, %1, off sc0 sc1"
                     :: "v"(&flags[0]), "v"(one) : "memory");
    }
}

// ---------------- fused residual + LayerNorm ------------------------------
__global__ __launch_bounds__(256) void fused_ln(
    const float* __restrict__ x,
    const __bf16* __restrict__ attn,
    const float* __restrict__ gam,
    const float* __restrict__ bet,
    float* __restrict__ out)
{
    const int row = blockIdx.x;
    const int t = threadIdx.x;
    const size_t base = (size_t)row * DH + t * 4;
    float4 xv = *(const float4*)(x + base);
    bf16x4 av = *(const bf16x4*)(attn + base);
    float v0 = xv.x + (float)av[0];
    float v1 = xv.y + (float)av[1];
    float v2 = xv.z + (float)av[2];
    float v3 = xv.w + (float)av[3];
    float s1 = v0 + v1 + v2 + v3;
    float s2 = v0 * v0 + v1 * v1 + v2 * v2 + v3 * v3;
#pragma unroll
    for (int off = 32; off > 0; off >>= 1) {
        s1 += __shfl_xor(s1, off);
        s2 += __shfl_xor(s2, off);
    }
    __shared__ float red[8];
    const int w = t >> 6, l = t & 63;
    if (l == 0) { red[w] = s1; red[4 + w] = s2; }
    __syncthreads();
    float S1 = red[0] + red[1] + red[2] + red[3];
    float S2 = red[4] + red[5] + red[6] + red[7];
    const float mu = S1 * (1.0f / 1024.0f);
    const float var = S2 * (1.0f / 1024.0f) - mu * mu;
    const float rs = rsqrtf(var + 1e-5f);
    const int c = t * 4;
    float4 gv = *(const float4*)(gam + c);
    float4 bv = *(const float4*)(bet + c);
    float4 o;
    o.x = (v0 - mu) * rs * gv.x + bv.x;
    o.y = (v1 - mu) * rs * gv.y + bv.y;
    o.z = (v2 - mu) * rs * gv.z + bv.z;
    o.w = (v3 - mu) * rs * gv.w + bv.w;
    *(float4*)(out + base) = o;
}

// ---------------- launcher -------------------------------------------------
extern "C" void kernel_launch(void* const* d_in, const int* in_sizes, int n_in,
                              void* d_out, int out_size, void* d_ws, size_t ws_size,
                              hipStream_t stream)
{
    const float* x    = (const float*)d_in[0];
    const float* Wih  = (const float*)d_in[1];
    const float* Whh  = (const float*)d_in[2];
    const float* bih  = (const float*)d_in[3];
    const float* bhh  = (const float*)d_in[4];
    const float* Wout = (const float*)d_in[5];
    const float* lng  = (const float*)d_in[6];
    const float* lnb  = (const float*)d_in[7];
    float* out = (float*)d_out;

    char* ws = (char*)d_ws;
    const size_t BIG = (size_t)MTOT * DH * sizeof(__bf16);  // 134217728
    __bf16* buf0   = (__bf16*)ws;                  // x_bf16, later reused for attn
    __bf16* pre    = (__bf16*)(ws + BIG);
    __bf16* hsbuf  = (__bf16*)(ws + 2 * BIG);
    __bf16* Wih_b  = (__bf16*)(ws + 3 * BIG);
    __bf16* Whh_b  = Wih_b + (size_t)DH * DH;
    __bf16* Wout_b = Whh_b + (size_t)DH * DH;
    float*  bias   = (float*)(Wout_b + (size_t)DH * DH);
    int*    flags  = (int*)(bias + DH);

    prep_kernel<<<1024, 256, 0, stream>>>(Wih, Whh, Wout, bih, bhh,
                                          Wih_b, Whh_b, Wout_b, bias, flags);
    cvt_bf16_x<<<32768, 256, 0, stream>>>(x, buf0);
    // clear hs: tag bits 00 never match a valid epoch (kills poison + stale replays)
    hipMemsetAsync(hsbuf, 0, BIG, stream);
    gemm_bt<<<4096, 256, 0, stream>>>(buf0, Wih_b, bias, pre, MTOT, DH, DH);
    rnn_scan<<<NWORK + NFILL, 512, 0, stream>>>(Whh_b, pre, hsbuf, flags);
    gemm_bt<<<4096, 256, 0, stream>>>(hsbuf, Wout_b, nullptr, buf0, MTOT, DH, DH);
    fused_ln<<<65536, 256, 0, stream>>>(x, buf0, lng, lnb, out);
}

// Round 10
// 8404.153 us; speedup vs baseline: 12.0496x; 1.0367x over previous
//
#include <hip/hip_runtime.h>
#include <hip/hip_bf16.h>

typedef __bf16 bf16x8 __attribute__((ext_vector_type(8)));
typedef __bf16 bf16x4 __attribute__((ext_vector_type(4)));
typedef float  f32x4  __attribute__((ext_vector_type(4)));
typedef unsigned int u32x2 __attribute__((ext_vector_type(2)));
typedef unsigned int u32x4 __attribute__((ext_vector_type(4)));

#define NSTEP 2048
#define NB    32     // batch
#define DH    1024   // hidden = d_model = d_res
#define MTOT  (NSTEP * NB)   // 65536
#define NWORK 16     // worker WGs in rnn_scan
#define NFILL 208    // clock-pinning filler WGs (16+208=224 < 256 CUs -> all resident)
#define FILLER_CAP 60000

__device__ __forceinline__ f32x4 mfma16(bf16x8 a, bf16x8 b, f32x4 c) {
    return __builtin_amdgcn_mfma_f32_16x16x32_bf16(a, b, c, 0, 0, 0);
}

__device__ __forceinline__ void load_lds16(const __bf16* g, void* l) {
    __builtin_amdgcn_global_load_lds(
        (const __attribute__((address_space(1))) void*)g,
        (__attribute__((address_space(3))) void*)l, 16, 0, 0);
}

__device__ __forceinline__ float tanh_fast(float x) {
    float e = exp2f(x * 2.8853900817779268f);
    return 1.0f - 2.0f * __builtin_amdgcn_rcpf(e + 1.0f);
}

// ---------------- prep: convert weights to bf16, sum biases, zero flags ----
__global__ __launch_bounds__(256) void prep_kernel(
    const float* __restrict__ Wih, const float* __restrict__ Whh,
    const float* __restrict__ Wout, const float* __restrict__ bih,
    const float* __restrict__ bhh,
    __bf16* __restrict__ Wih_b, __bf16* __restrict__ Whh_b,
    __bf16* __restrict__ Wout_b, float* __restrict__ bias,
    int* __restrict__ flags)
{
    const int i = blockIdx.x * 256 + threadIdx.x;   // 0..262143
    const size_t off = (size_t)i * 4;
    {
        float4 a = *(const float4*)(Wih + off);
        bf16x4 o = {(__bf16)a.x, (__bf16)a.y, (__bf16)a.z, (__bf16)a.w};
        *(bf16x4*)(Wih_b + off) = o;
    }
    {
        float4 a = *(const float4*)(Whh + off);
        bf16x4 o = {(__bf16)a.x, (__bf16)a.y, (__bf16)a.z, (__bf16)a.w};
        *(bf16x4*)(Whh_b + off) = o;
    }
    {
        float4 a = *(const float4*)(Wout + off);
        bf16x4 o = {(__bf16)a.x, (__bf16)a.y, (__bf16)a.z, (__bf16)a.w};
        *(bf16x4*)(Wout_b + off) = o;
    }
    if (i < DH) bias[i] = bih[i] + bhh[i];
    if (i < 64) {
        int z = 0;
        asm volatile("global_store_dword %0, %1, off sc0 sc1"
                     :: "v"(&flags[i]), "v"(z) : "memory");
    }
}

// ---------------- x fp32 -> bf16 -----------------------------------------
__global__ __launch_bounds__(256) void cvt_bf16_x(
    const float* __restrict__ in, __bf16* __restrict__ outb)
{
    const size_t i = ((size_t)blockIdx.x * 256 + threadIdx.x) * 8;
    float4 a = *(const float4*)(in + i);
    float4 b = *(const float4*)(in + i + 4);
    bf16x8 o = { (__bf16)a.x, (__bf16)a.y, (__bf16)a.z, (__bf16)a.w,
                 (__bf16)b.x, (__bf16)b.y, (__bf16)b.z, (__bf16)b.w };
    *(bf16x8*)(outb + i) = o;
}

// ---------------- bf16 GEMM, C = A(MxK) * B(NxK)^T (+bias), bf16 out ------
__global__ __launch_bounds__(256) void gemm_bt(
    const __bf16* __restrict__ A,
    const __bf16* __restrict__ B,
    const float*  __restrict__ bias,
    __bf16* __restrict__ C,
    int M, int N, int K)
{
    __shared__ __bf16 sA[128 * 64];
    __shared__ __bf16 sB[128 * 64];
    const int nTn = N >> 7;
    const int tm = (int)(blockIdx.x / nTn) << 7;
    const int tn = (int)(blockIdx.x % nTn) << 7;
    const int t = threadIdx.x;
    const int w = t >> 6, l = t & 63;
    const int wy = w & 1, wx = w >> 1;
    const int l16 = l & 15, lhi = l >> 4;
    const int rw = t >> 3;
    const int kc = (t & 7) << 3;

    const __bf16* ga = A + (size_t)(tm + rw) * K + kc;
    const __bf16* gb = B + (size_t)(tn + rw) * K + kc;
    char* lA = (char*)sA + (w * 8) * 128;
    char* lB = (char*)sB + (w * 8) * 128;

    f32x4 acc[4][4] = {};

    for (int k0 = 0; k0 < K; k0 += 64) {
#pragma unroll
        for (int i = 0; i < 4; ++i) {
            load_lds16(ga + (size_t)(i * 32) * K + k0, lA + i * 32 * 128);
            load_lds16(gb + (size_t)(i * 32) * K + k0, lB + i * 32 * 128);
        }
        asm volatile("s_waitcnt vmcnt(0)" ::: "memory");
        __syncthreads();
#pragma unroll
        for (int kk = 0; kk < 2; ++kk) {
            bf16x8 af[4], bfr[4];
#pragma unroll
            for (int i = 0; i < 4; ++i) {
                af[i]  = *(const bf16x8*)(sA + (wy * 64 + i * 16 + l16) * 64 + kk * 32 + lhi * 8);
                bfr[i] = *(const bf16x8*)(sB + (wx * 64 + i * 16 + l16) * 64 + kk * 32 + lhi * 8);
            }
#pragma unroll
            for (int i = 0; i < 4; ++i)
#pragma unroll
                for (int j = 0; j < 4; ++j)
                    acc[i][j] = mfma16(af[i], bfr[j], acc[i][j]);
        }
        __syncthreads();
    }
#pragma unroll
    for (int j = 0; j < 4; ++j) {
        const int col = tn + wx * 64 + j * 16 + l16;
        const float bv = bias ? bias[col] : 0.0f;
#pragma unroll
        for (int i = 0; i < 4; ++i) {
            __bf16* cp = C + (size_t)(tm + wy * 64 + i * 16 + lhi * 4) * N + col;
#pragma unroll
            for (int r = 0; r < 4; ++r)
                cp[(size_t)r * N] = (__bf16)(acc[i][j][r] + bv);
        }
    }
}

// ---------------- persistent RNN scan: LDS-staged, MALL-hot exchange ------
// 16 worker WGs x 8 waves. WG g owns j-cols [g*64,(g+1)*64). Swapped MFMA
// (verified): D[j][b]; lane produces 4 j-consecutive bf16 = one dwordx2.
//
// R10 change: exchange moves to a 128KB ping-pong buffer hx[2][32][1024]
// (stays MALL-resident -> uncached loads ~L3 latency, not DRAM; R9's 447KB/
// step HBM fetch showed the big hs buffer streamed through MALL). hs output
// for the GEMM is written with PLAIN cached stores (off critical path;
// kernel boundary publishes it). Tag epoch flips every 2 steps
// (((s>>1)&1)+1), matching the slot-reuse distance; slot overwrite is safe:
// a producer reaches step s+1 only after seeing ALL h_s tags, and any WG
// that stored h_s has already finished reading h_{s-1} (program order).
// Stage: each thread retry-loads its 8x16B slice until tags pass (load IS
// the poll), ds_writes XOR-swizzled, one barrier, 8 waves consume from LDS.
// Fillers pin SCLK on remaining CUs (R6-proven).
#define LDU(d, p) asm volatile("global_load_dwordx4 %0, %1, off sc0 sc1" \
                               : "=v"(d) : "v"(p) : "memory");

__global__ __launch_bounds__(512, 2) void rnn_scan(
    const __bf16* __restrict__ Whh,   // [1024][1024] bf16 (row j, col k)
    const __bf16* __restrict__ pre,   // [2048][32][1024] bf16
    __bf16* __restrict__ hs,          // [2048][32][1024] bf16 (plain, for GEMM)
    __bf16* __restrict__ hx,          // [2][32][1024] bf16 ping-pong exchange
    int* __restrict__ flags)          // [0] = done flag
{
    const int gb = blockIdx.x;
    if (gb >= NWORK) {
        // ---- clock-pinning filler ----
        float a = (float)(threadIdx.x + gb) * 1.0e-6f + 1.0f;
        const float m = 1.000001f, d = 0.999999f;
        const int* dp = flags;
        for (int it = 0; it < FILLER_CAP; ++it) {
#pragma unroll
            for (int u = 0; u < 128; ++u) {
                a = __builtin_fmaf(a, m, 1.0e-12f);
                a = __builtin_fmaf(a, d, -1.0e-12f);
            }
            if ((it & 15) == 0) {
                int dn;
                asm volatile("global_load_dword %0, %1, off sc0 sc1\n\t"
                             "s_waitcnt vmcnt(0)"
                             : "=v"(dn) : "v"(dp) : "memory");
                if (dn != 0) break;
            }
        }
        asm volatile("" :: "v"(a));
        return;
    }

    __shared__ char slab[2][65536];    // double-buffered h slab [32 b][1024 j]
    const int t = threadIdx.x;         // 0..511
    const int w = t >> 6;              // 0..7
    const int l = t & 63;
    const int mhalf = w & 1;
    const int jg = w >> 1;             // 0..3
    const int j0 = gb * 64 + jg * 16;  // wave's 16 output cols (W rows)
    const int l16 = l & 15;
    const int lhi = l >> 4;
    const int b  = mhalf * 16 + l16;   // batch row this lane produces/consumes
    const int jc = j0 + lhi * 4;       // 4 output cols this lane stores

    // A-operand (W rows j0..j0+15): wreg[c] covers k in [c*32, c*32+32)
    bf16x8 wreg[32];
    {
        const __bf16* wb = Whh + (size_t)(j0 + l16) * DH + lhi * 8;
#pragma unroll
        for (int c = 0; c < 32; ++c)
            wreg[c] = *(const bf16x8*)(wb + c * 32);
    }

    // LDS read geometry for this lane's B-fragments: row=b, swizzle by b&7
    const unsigned rbase = (unsigned)b * 2048 + (unsigned)lhi * 16;
    const unsigned rx = (unsigned)((b & 7) << 4);

    for (int s = 0; s < NSTEP; ++s) {
        bf16x4 pv = *(const bf16x4*)(pre + ((size_t)s * NB + b) * DH + jc);

        f32x4 acc0 = {0.f, 0.f, 0.f, 0.f}, acc1 = acc0, acc2 = acc0, acc3 = acc0;
        int bi = 0;

        if (s > 0) {
            const int sl = s - 1;
            bi = sl & 1;
            const unsigned rep = (unsigned)(((sl >> 1) & 1) + 1) * 0x00010001u;
            const char* sp = (const char*)hx + ((size_t)(sl & 1) << 16) + (size_t)t * 16;
            const char* p0 = sp;
            const char* p1 = sp + 8192;
            const char* p2 = sp + 16384;
            const char* p3 = sp + 24576;
            const char* p4 = sp + 32768;
            const char* p5 = sp + 40960;
            const char* p6 = sp + 49152;
            const char* p7 = sp + 57344;
            u32x4 st[8];
            for (;;) {
                LDU(st[0], p0) LDU(st[1], p1) LDU(st[2], p2) LDU(st[3], p3)
                LDU(st[4], p4) LDU(st[5], p5) LDU(st[6], p6) LDU(st[7], p7)
                asm volatile("s_waitcnt vmcnt(0)" ::: "memory");
                __builtin_amdgcn_sched_barrier(0);
                unsigned bad = 0;
#pragma unroll
                for (int i = 0; i < 8; ++i)
                    bad |= (st[i][0] ^ rep) | (st[i][1] ^ rep)
                         | (st[i][2] ^ rep) | (st[i][3] ^ rep);
                if (__all((bad & 0x00030003u) == 0u)) break;
            }
            __builtin_amdgcn_sched_barrier(0);
            // ds_write slice (XOR-swizzled: row stride 2048B would 16-way conflict)
#pragma unroll
            for (int i = 0; i < 8; ++i) {
                unsigned byte = (unsigned)t * 16 + (unsigned)i * 8192;
                unsigned row = byte >> 11;
                unsigned swz = byte ^ ((row & 7) << 4);
                *(u32x4*)(&slab[bi][swz]) = st[i];
            }
            __syncthreads();
            // consume: this wave's batch-half rows, full k, from LDS
#pragma unroll
            for (int c = 0; c < 32; c += 4) {
                bf16x8 h0 = *(const bf16x8*)(&slab[bi][(rbase + (unsigned)(c + 0) * 64) ^ rx]);
                bf16x8 h1 = *(const bf16x8*)(&slab[bi][(rbase + (unsigned)(c + 1) * 64) ^ rx]);
                bf16x8 h2 = *(const bf16x8*)(&slab[bi][(rbase + (unsigned)(c + 2) * 64) ^ rx]);
                bf16x8 h3 = *(const bf16x8*)(&slab[bi][(rbase + (unsigned)(c + 3) * 64) ^ rx]);
                acc0 = mfma16(wreg[c + 0], h0, acc0);
                acc1 = mfma16(wreg[c + 1], h1, acc1);
                acc2 = mfma16(wreg[c + 2], h2, acc2);
                acc3 = mfma16(wreg[c + 3], h3, acc3);
            }
        }
        f32x4 accs = (acc0 + acc1) + (acc2 + acc3);

        float h0 = tanh_fast(accs[0] + (float)pv[0]);
        float h1 = tanh_fast(accs[1] + (float)pv[1]);
        float h2 = tanh_fast(accs[2] + (float)pv[2]);
        float h3 = tanh_fast(accs[3] + (float)pv[3]);
        // tag low 2 bits of each bf16 with epoch (round to nearest 4 ulp);
        // epoch flips every 2 steps = slot reuse distance
        const unsigned tag = (unsigned)(((s >> 1) & 1) + 1);
        unsigned u0 = (unsigned)__builtin_bit_cast(unsigned short, (__bf16)h0);
        unsigned u1 = (unsigned)__builtin_bit_cast(unsigned short, (__bf16)h1);
        unsigned u2 = (unsigned)__builtin_bit_cast(unsigned short, (__bf16)h2);
        unsigned u3 = (unsigned)__builtin_bit_cast(unsigned short, (__bf16)h3);
        u0 = ((u0 + 2u) & 0xFFFCu) | tag;
        u1 = ((u1 + 2u) & 0xFFFCu) | tag;
        u2 = ((u2 + 2u) & 0xFFFCu) | tag;
        u3 = ((u3 + 2u) & 0xFFFCu) | tag;
        u32x2 uval;
        uval[0] = u0 | (u1 << 16);
        uval[1] = u2 | (u3 << 16);
        // exchange store: uncached, MALL-hot ping-pong slot
        __bf16* ox = hx + ((size_t)(s & 1) * NB + b) * DH + jc;
        asm volatile("global_store_dwordx2 %0, %1, off sc0 sc1"
                     :: "v"(ox), "v"(uval) : "memory");
        // output store: plain cached (GEMM reads it after kernel boundary)
        *(u32x2*)(hs + ((size_t)s * NB + b) * DH + jc) = uval;
        // no drain, no flags: consumers validate the data itself
    }
    if (gb == 0 && t == 0) {
        int one = 1;
        asm volatile("global_store_dword %0, %1, off sc0 sc1"
                     :: "v"(&flags[0]), "v"(one) : "memory");
    }
}

// ---------------- fused residual + LayerNorm ------------------------------
__global__ __launch_bounds__(256) void fused_ln(
    const float* __restrict__ x,
    const __bf16* __restrict__ attn,
    const float* __restrict__ gam,
    const float* __restrict__ bet,
    float* __restrict__ out)
{
    const int row = blockIdx.x;
    const int t = threadIdx.x;
    const size_t base = (size_t)row * DH + t * 4;
    float4 xv = *(const float4*)(x + base);
    bf16x4 av = *(const bf16x4*)(attn + base);
    float v0 = xv.x + (float)av[0];
    float v1 = xv.y + (float)av[1];
    float v2 = xv.z + (float)av[2];
    float v3 = xv.w + (float)av[3];
    float s1 = v0 + v1 + v2 + v3;
    float s2 = v0 * v0 + v1 * v1 + v2 * v2 + v3 * v3;
#pragma unroll
    for (int off = 32; off > 0; off >>= 1) {
        s1 += __shfl_xor(s1, off);
        s2 += __shfl_xor(s2, off);
    }
    __shared__ float red[8];
    const int w = t >> 6, l = t & 63;
    if (l == 0) { red[w] = s1; red[4 + w] = s2; }
    __syncthreads();
    float S1 = red[0] + red[1] + red[2] + red[3];
    float S2 = red[4] + red[5] + red[6] + red[7];
    const float mu = S1 * (1.0f / 1024.0f);
    const float var = S2 * (1.0f / 1024.0f) - mu * mu;
    const float rs = rsqrtf(var + 1e-5f);
    const int c = t * 4;
    float4 gv = *(const float4*)(gam + c);
    float4 bv = *(const float4*)(bet + c);
    float4 o;
    o.x = (v0 - mu) * rs * gv.x + bv.x;
    o.y = (v1 - mu) * rs * gv.y + bv.y;
    o.z = (v2 - mu) * rs * gv.z + bv.z;
    o.w = (v3 - mu) * rs * gv.w + bv.w;
    *(float4*)(out + base) = o;
}

// ---------------- launcher -------------------------------------------------
extern "C" void kernel_launch(void* const* d_in, const int* in_sizes, int n_in,
                              void* d_out, int out_size, void* d_ws, size_t ws_size,
                              hipStream_t stream)
{
    const float* x    = (const float*)d_in[0];
    const float* Wih  = (const float*)d_in[1];
    const float* Whh  = (const float*)d_in[2];
    const float* bih  = (const float*)d_in[3];
    const float* bhh  = (const float*)d_in[4];
    const float* Wout = (const float*)d_in[5];
    const float* lng  = (const float*)d_in[6];
    const float* lnb  = (const float*)d_in[7];
    float* out = (float*)d_out;

    char* ws = (char*)d_ws;
    const size_t BIG = (size_t)MTOT * DH * sizeof(__bf16);  // 134217728
    __bf16* buf0   = (__bf16*)ws;                  // x_bf16, later reused for attn
    __bf16* pre    = (__bf16*)(ws + BIG);
    __bf16* hsbuf  = (__bf16*)(ws + 2 * BIG);
    __bf16* Wih_b  = (__bf16*)(ws + 3 * BIG);
    __bf16* Whh_b  = Wih_b + (size_t)DH * DH;
    __bf16* Wout_b = Whh_b + (size_t)DH * DH;
    float*  bias   = (float*)(Wout_b + (size_t)DH * DH);
    int*    flags  = (int*)(bias + DH);
    __bf16* hx     = (__bf16*)(ws + 3 * BIG + 8 * 1024 * 1024);  // 128KB ping-pong

    prep_kernel<<<1024, 256, 0, stream>>>(Wih, Whh, Wout, bih, bhh,
                                          Wih_b, Whh_b, Wout_b, bias, flags);
    cvt_bf16_x<<<32768, 256, 0, stream>>>(x, buf0);
    // clear hx: tag bits 00 never match a valid epoch (kills poison + stale replays)
    hipMemsetAsync(hx, 0, 2 * NB * DH * sizeof(__bf16), stream);
    gemm_bt<<<4096, 256, 0, stream>>>(buf0, Wih_b, bias, pre, MTOT, DH, DH);
    rnn_scan<<<NWORK + NFILL, 512, 0, stream>>>(Whh_b, pre, hsbuf, hx, flags);
    gemm_bt<<<4096, 256, 0, stream>>>(hsbuf, Wout_b, nullptr, buf0, MTOT, DH, DH);
    fused_ln<<<65536, 256, 0, stream>>>(x, buf0, lng, lnb, out);
}